// Round 19
// baseline (53.400 us; speedup 1.0000x reference)
//
#include <hip/hip_runtime.h>

// (min,+) DP, wave-specialized, 6 waves/block, 2 images, grid=256 (1/CU).
// Wave->SIMD is round-robin (wid%4), so placing the CHAIN waves at wid 2,3
// gives each chain a PRIVATE SIMD (only 6 waves: SIMD2/SIMD3 host one wave
// each). Preps (wid 0,1,4,5; 2 per image, 8 rows/chunk) pair on SIMD0/1.
//   wid 2: chain img A   wid 3: chain img B
//   wid 0: prep  img A rows 0-7    wid 4: prep img A rows 8-15
//   wid 1: prep  img B rows 0-7    wid 5: prep img B rows 8-15
// Fused in-place DPP scans (R18, -6.3us). CH=16, LDS 64KB, coop chunk-0
// (6/5/5 rows per image's 3 waves). Spill-free prep arrays (R16 lesson).

#define HH 256
#define WW 256
#define CH 16          // rows per chunk
#define NCH 16         // chunks per image
#define NULLV 1e30f

template<int CTRL, int ROWM>
__device__ __forceinline__ float dpp_mov(float x, float oldv) {
    return __builtin_bit_cast(float, __builtin_amdgcn_update_dpp(
        __builtin_bit_cast(int, oldv), __builtin_bit_cast(int, x),
        CTRL, ROWM, 0xF, false));
}

// 64-lane inclusive min-scan: 6 fused in-place DPP steps.
// Write-suppression (no bound_ctrl) = identity for invalid-source lanes.
__device__ __forceinline__ float wave_iscan_min(float x) {
    asm volatile(
        "s_nop 1\n\t"
        "v_min_f32_dpp %0, %0, %0 row_shr:1  row_mask:0xf bank_mask:0xf\n\t"
        "s_nop 1\n\t"
        "v_min_f32_dpp %0, %0, %0 row_shr:2  row_mask:0xf bank_mask:0xf\n\t"
        "s_nop 1\n\t"
        "v_min_f32_dpp %0, %0, %0 row_shr:4  row_mask:0xf bank_mask:0xf\n\t"
        "s_nop 1\n\t"
        "v_min_f32_dpp %0, %0, %0 row_shr:8  row_mask:0xf bank_mask:0xf\n\t"
        "s_nop 1\n\t"
        "v_min_f32_dpp %0, %0, %0 row_bcast:15 row_mask:0xa bank_mask:0xf\n\t"
        "s_nop 1\n\t"
        "v_min_f32_dpp %0, %0, %0 row_bcast:31 row_mask:0xc bank_mask:0xf"
        : "+v"(x));
    return x;
}

// 64-lane inclusive add-scan: fused in-place, bound_ctrl:0 (reads 0 = id).
__device__ __forceinline__ float wave_iscan_add(float x) {
    asm volatile(
        "s_nop 1\n\t"
        "v_add_f32_dpp %0, %0, %0 row_shr:1  row_mask:0xf bank_mask:0xf bound_ctrl:0\n\t"
        "s_nop 1\n\t"
        "v_add_f32_dpp %0, %0, %0 row_shr:2  row_mask:0xf bank_mask:0xf bound_ctrl:0\n\t"
        "s_nop 1\n\t"
        "v_add_f32_dpp %0, %0, %0 row_shr:4  row_mask:0xf bank_mask:0xf bound_ctrl:0\n\t"
        "s_nop 1\n\t"
        "v_add_f32_dpp %0, %0, %0 row_shr:8  row_mask:0xf bank_mask:0xf bound_ctrl:0\n\t"
        "s_nop 1\n\t"
        "v_add_f32_dpp %0, %0, %0 row_bcast:15 row_mask:0xa bank_mask:0xf bound_ctrl:0\n\t"
        "s_nop 1\n\t"
        "v_add_f32_dpp %0, %0, %0 row_bcast:31 row_mask:0xc bank_mask:0xf bound_ctrl:0"
        : "+v"(x));
    return x;
}

__device__ __forceinline__ float softplus_f(float x) {
    float ax = fabsf(x);
    float t  = __expf(-ax);
    return fmaxf(x, 0.0f) + __logf(1.0f + t);
}

// full-row cumsum of softplus for one row; returns S at cols 4l..4l+3
__device__ __forceinline__ float4 prep_row(float4 c) {
    float t0 = softplus_f(c.x);
    float t1 = t0 + softplus_f(c.y);
    float t2 = t1 + softplus_f(c.z);
    float t3 = t2 + softplus_f(c.w);
    float s    = wave_iscan_add(t3);
    float soff = dpp_mov<0x138, 0xF>(s, 0.0f);  // wave_shr:1, lane0 -> 0
    return make_float4(soff + t0, soff + t1, soff + t2, soff + t3);
}

template<int NR>
__device__ __forceinline__ void load_rows(const float4* gp, int r0, float4* L) {
#pragma unroll
    for (int i = 0; i < NR; ++i) L[i] = gp[(size_t)(r0 + i) * 64];
}

template<int NR>
__device__ __forceinline__ void prep_store(const float4* L, float* dst, int lane) {
#pragma unroll
    for (int i = 0; i < NR; ++i)
        *reinterpret_cast<float4*>(&dst[i * WW + lane * 4]) = prep_row(L[i]);
}

// steady-state prep worker: NR rows at chunk-offset row0, chunks 1..NCH-1,
// next chunk's loads issued before current chunk's trans-heavy compute.
template<int NR>
__device__ __forceinline__ void prep_run(const float4* gp, int row0,
                                         float* base0, float* base1, int lane) {
    float4 L[NR];
    load_rows<NR>(gp, CH + row0, L);           // chunk 1
    __syncthreads();                           // B0 (chunk 0 published by all)
    for (int k = 1; k < NCH; ++k) {
        float4 N[NR];
        if (k + 1 < NCH) load_rows<NR>(gp, (k + 1) * CH + row0, N);
        prep_store<NR>(L, (k & 1) ? base1 : base0, lane);
        __syncthreads();                       // Bk: chunk k ready
        if (k + 1 < NCH) {
#pragma unroll
            for (int i = 0; i < NR; ++i) L[i] = N[i];
        }
    }
}

__global__ __launch_bounds__(384, 1) void dp_kernel(const float* __restrict__ img,
                                                    float* __restrict__ out) {
    const int tid = threadIdx.x;
    const int wid = tid >> 6;
    const int lane = tid & 63;

    // [image][buffer][row][col] -> 64 KB
    __shared__ __align__(16) float sbuf[2][2][CH][WW];

    const int imgi = wid & 1;                  // even waves -> img A, odd -> B
    const float* gbase = img + (size_t)(2 * blockIdx.x + imgi) * HH * WW;
    const float4* gp = reinterpret_cast<const float4*>(gbase) + lane;

    if (wid == 2 || wid == 3) {
        // ------------- chain waves (PRIVATE SIMD each: wid%4 = 2,3) -------------
        {   // cooperative chunk-0: chain preps rows 0-5
            float4 C[6];
            load_rows<6>(gp, 0, C);
            prep_store<6>(C, &sbuf[imgi][0][0][0], lane);
        }
        __syncthreads();                       // B0: chunk 0 ready
        __builtin_amdgcn_s_setprio(1);

        float v0, v1, v2, v3;
        auto row_step = [&](const float4& S) {
            float soff = dpp_mov<0x138, 0xF>(S.w, 0.0f);  // S[4l-1]
            float vm1  = dpp_mov<0x138, 0xF>(v3, NULLV);  // v[4l-1]
            float B0 = fminf(v0, vm1) - soff;
            float B1 = fminf(v1, v0) - S.x;
            float B2 = fminf(v2, v1) - S.y;
            float B3 = fminf(v3, v2) - S.z;
            float m1 = fminf(B0, B1);
            float p  = fminf(B2, B3);
            float m2 = fminf(m1, B2);
            float m3 = fminf(m1, p);           // depth-2 tree
            float mm   = wave_iscan_min(m3);   // fused DPP scan (asm)
            float moff = dpp_mov<0x138, 0xF>(mm, NULLV);
            v0 = S.x + fminf(moff, B0);
            v1 = S.y + fminf(moff, m1);
            v2 = S.z + fminf(moff, m2);
            v3 = S.w + fminf(moff, m3);
        };

#define RD8(P, buf, r0)                                                  \
    P##0 = *reinterpret_cast<const float4*>(&(buf)[(r0) + 0][lane * 4]); \
    P##1 = *reinterpret_cast<const float4*>(&(buf)[(r0) + 1][lane * 4]); \
    P##2 = *reinterpret_cast<const float4*>(&(buf)[(r0) + 2][lane * 4]); \
    P##3 = *reinterpret_cast<const float4*>(&(buf)[(r0) + 3][lane * 4]); \
    P##4 = *reinterpret_cast<const float4*>(&(buf)[(r0) + 4][lane * 4]); \
    P##5 = *reinterpret_cast<const float4*>(&(buf)[(r0) + 5][lane * 4]); \
    P##6 = *reinterpret_cast<const float4*>(&(buf)[(r0) + 6][lane * 4]); \
    P##7 = *reinterpret_cast<const float4*>(&(buf)[(r0) + 7][lane * 4]);
#define ST8(P)                                                           \
    row_step(P##0); row_step(P##1); row_step(P##2); row_step(P##3);      \
    row_step(P##4); row_step(P##5); row_step(P##6); row_step(P##7);

        float4 A0, A1, A2, A3, A4, A5, A6, A7;
        float4 B0, B1, B2, B3, B4, B5, B6, B7;

        // chunk 0 (rows 0..15; peel row-0 init)
        {
            const float(*buf)[WW] = sbuf[imgi][0];
            RD8(A, buf, 0); RD8(B, buf, 8);
            v0 = A0.x; v1 = A0.y; v2 = A0.z; v3 = A0.w;
            row_step(A1); row_step(A2); row_step(A3);
            row_step(A4); row_step(A5); row_step(A6); row_step(A7);
            ST8(B);
        }
        // chunks 1..15
        for (int k = 1; k < NCH; ++k) {
            __syncthreads();                   // Bk
            const float(*buf)[WW] = sbuf[imgi][k & 1];
            RD8(A, buf, 0); RD8(B, buf, 8);
            ST8(A);
            ST8(B);
        }
#undef RD8
#undef ST8
        if (lane == 63) out[2 * blockIdx.x + imgi] = v3;
    } else if (wid < 2) {
        // ------------- prep wave 1 of image (wid 0,1): steady rows 0-7 -------------
        {   // cooperative chunk-0: rows 6-10
            float4 C[5];
            load_rows<5>(gp, 6, C);
            prep_store<5>(C, &sbuf[imgi][0][6][0], lane);
        }
        prep_run<8>(gp, 0, &sbuf[imgi][0][0][0], &sbuf[imgi][1][0][0], lane);
    } else {
        // ------------- prep wave 2 of image (wid 4,5): steady rows 8-15 -------------
        {   // cooperative chunk-0: rows 11-15
            float4 C[5];
            load_rows<5>(gp, 11, C);
            prep_store<5>(C, &sbuf[imgi][0][11][0], lane);
        }
        prep_run<8>(gp, 8, &sbuf[imgi][0][8][0], &sbuf[imgi][1][8][0], lane);
    }
}

extern "C" void kernel_launch(void* const* d_in, const int* in_sizes, int n_in,
                              void* d_out, int out_size, void* d_ws, size_t ws_size,
                              hipStream_t stream) {
    const float* img = (const float*)d_in[0];
    float* out = (float*)d_out;
    dp_kernel<<<out_size / 2, 384, 0, stream>>>(img, out);
}

// Round 20
// 38.350 us; speedup vs baseline: 1.3924x; 1.3924x over previous
//
#include <hip/hip_runtime.h>

// (min,+) DP, wave-specialized. ONE image/block, 7 waves, grid=512 (2/CU).
// Wave->SIMD is wid%4, so per CU: SIMD3 = the two blocks' CHAIN waves
// (wid3) -- two latency-bound chains interleave, hiding each other's
// dependency bubbles; SIMD0-2 = 12 prep waves (6/image, ~2.7 rows/chunk).
// Chains never share issue slots with trans-heavy preps (R19's failure),
// and prep capacity stays ample (R13/R19's failure).
// Fused in-place DPP scans (R18). CH=16, LDS 32KB/block, coop chunk-0.

#define HH 256
#define WW 256
#define CH 16          // rows per chunk
#define NCH 16         // chunks per image
#define NULLV 1e30f

template<int CTRL, int ROWM>
__device__ __forceinline__ float dpp_mov(float x, float oldv) {
    return __builtin_bit_cast(float, __builtin_amdgcn_update_dpp(
        __builtin_bit_cast(int, oldv), __builtin_bit_cast(int, x),
        CTRL, ROWM, 0xF, false));
}

// 64-lane inclusive min-scan: 6 fused in-place DPP steps.
// Write-suppression (no bound_ctrl) = identity for invalid-source lanes.
__device__ __forceinline__ float wave_iscan_min(float x) {
    asm volatile(
        "s_nop 1\n\t"
        "v_min_f32_dpp %0, %0, %0 row_shr:1  row_mask:0xf bank_mask:0xf\n\t"
        "s_nop 1\n\t"
        "v_min_f32_dpp %0, %0, %0 row_shr:2  row_mask:0xf bank_mask:0xf\n\t"
        "s_nop 1\n\t"
        "v_min_f32_dpp %0, %0, %0 row_shr:4  row_mask:0xf bank_mask:0xf\n\t"
        "s_nop 1\n\t"
        "v_min_f32_dpp %0, %0, %0 row_shr:8  row_mask:0xf bank_mask:0xf\n\t"
        "s_nop 1\n\t"
        "v_min_f32_dpp %0, %0, %0 row_bcast:15 row_mask:0xa bank_mask:0xf\n\t"
        "s_nop 1\n\t"
        "v_min_f32_dpp %0, %0, %0 row_bcast:31 row_mask:0xc bank_mask:0xf"
        : "+v"(x));
    return x;
}

// 64-lane inclusive add-scan: fused in-place, bound_ctrl:0 (reads 0 = id).
__device__ __forceinline__ float wave_iscan_add(float x) {
    asm volatile(
        "s_nop 1\n\t"
        "v_add_f32_dpp %0, %0, %0 row_shr:1  row_mask:0xf bank_mask:0xf bound_ctrl:0\n\t"
        "s_nop 1\n\t"
        "v_add_f32_dpp %0, %0, %0 row_shr:2  row_mask:0xf bank_mask:0xf bound_ctrl:0\n\t"
        "s_nop 1\n\t"
        "v_add_f32_dpp %0, %0, %0 row_shr:4  row_mask:0xf bank_mask:0xf bound_ctrl:0\n\t"
        "s_nop 1\n\t"
        "v_add_f32_dpp %0, %0, %0 row_shr:8  row_mask:0xf bank_mask:0xf bound_ctrl:0\n\t"
        "s_nop 1\n\t"
        "v_add_f32_dpp %0, %0, %0 row_bcast:15 row_mask:0xa bank_mask:0xf bound_ctrl:0\n\t"
        "s_nop 1\n\t"
        "v_add_f32_dpp %0, %0, %0 row_bcast:31 row_mask:0xc bank_mask:0xf bound_ctrl:0"
        : "+v"(x));
    return x;
}

__device__ __forceinline__ float softplus_f(float x) {
    float ax = fabsf(x);
    float t  = __expf(-ax);
    return fmaxf(x, 0.0f) + __logf(1.0f + t);
}

// full-row cumsum of softplus for one row; returns S at cols 4l..4l+3
__device__ __forceinline__ float4 prep_row(float4 c) {
    float t0 = softplus_f(c.x);
    float t1 = t0 + softplus_f(c.y);
    float t2 = t1 + softplus_f(c.z);
    float t3 = t2 + softplus_f(c.w);
    float s    = wave_iscan_add(t3);
    float soff = dpp_mov<0x138, 0xF>(s, 0.0f);  // wave_shr:1, lane0 -> 0
    return make_float4(soff + t0, soff + t1, soff + t2, soff + t3);
}

template<int NR>
__device__ __forceinline__ void load_rows(const float4* gp, int r0, float4* L) {
#pragma unroll
    for (int i = 0; i < NR; ++i) L[i] = gp[(size_t)(r0 + i) * 64];
}

template<int NR>
__device__ __forceinline__ void prep_store(const float4* L, float* dst, int lane) {
#pragma unroll
    for (int i = 0; i < NR; ++i)
        *reinterpret_cast<float4*>(&dst[i * WW + lane * 4]) = prep_row(L[i]);
}

// steady-state prep worker: NR rows at chunk-offset row0, chunks 1..NCH-1,
// next chunk's loads issued before current chunk's trans-heavy compute.
template<int NR>
__device__ __forceinline__ void prep_run(const float4* gp, int row0,
                                         float* base0, float* base1, int lane) {
    float4 L[NR];
    load_rows<NR>(gp, CH + row0, L);           // chunk 1
    __syncthreads();                           // B0 (chunk 0 published by all)
    for (int k = 1; k < NCH; ++k) {
        float4 N[NR];
        if (k + 1 < NCH) load_rows<NR>(gp, (k + 1) * CH + row0, N);
        prep_store<NR>(L, (k & 1) ? base1 : base0, lane);
        __syncthreads();                       // Bk: chunk k ready
        if (k + 1 < NCH) {
#pragma unroll
            for (int i = 0; i < NR; ++i) L[i] = N[i];
        }
    }
}

__global__ __launch_bounds__(448, 2) void dp_kernel(const float* __restrict__ img,
                                                    float* __restrict__ out) {
    const int tid = threadIdx.x;
    const int wid = tid >> 6;                  // 0..6; wid3 = chain (SIMD3)
    const int lane = tid & 63;

    // [buffer][row][col] -> 32 KB
    __shared__ __align__(16) float sbuf[2][CH][WW];

    const float* gbase = img + (size_t)blockIdx.x * HH * WW;
    const float4* gp = reinterpret_cast<const float4*>(gbase) + lane;

    if (wid == 3) {
        // ---------------- chain wave (SIMD3; co-tenant = other block's chain) ----------------
        {   // cooperative chunk-0: rows 0-1
            float4 C[2];
            load_rows<2>(gp, 0, C);
            prep_store<2>(C, &sbuf[0][0][0], lane);
        }
        __syncthreads();                       // B0: chunk 0 ready
        __builtin_amdgcn_s_setprio(1);

        float v0, v1, v2, v3;
        auto row_step = [&](const float4& S) {
            float soff = dpp_mov<0x138, 0xF>(S.w, 0.0f);  // S[4l-1]
            float vm1  = dpp_mov<0x138, 0xF>(v3, NULLV);  // v[4l-1]
            float B0 = fminf(v0, vm1) - soff;
            float B1 = fminf(v1, v0) - S.x;
            float B2 = fminf(v2, v1) - S.y;
            float B3 = fminf(v3, v2) - S.z;
            float m1 = fminf(B0, B1);
            float p  = fminf(B2, B3);
            float m2 = fminf(m1, B2);
            float m3 = fminf(m1, p);           // depth-2 tree
            float mm   = wave_iscan_min(m3);   // fused DPP scan (asm)
            float moff = dpp_mov<0x138, 0xF>(mm, NULLV);
            v0 = S.x + fminf(moff, B0);
            v1 = S.y + fminf(moff, m1);
            v2 = S.z + fminf(moff, m2);
            v3 = S.w + fminf(moff, m3);
        };

#define RD8(P, buf, r0)                                                  \
    P##0 = *reinterpret_cast<const float4*>(&(buf)[(r0) + 0][lane * 4]); \
    P##1 = *reinterpret_cast<const float4*>(&(buf)[(r0) + 1][lane * 4]); \
    P##2 = *reinterpret_cast<const float4*>(&(buf)[(r0) + 2][lane * 4]); \
    P##3 = *reinterpret_cast<const float4*>(&(buf)[(r0) + 3][lane * 4]); \
    P##4 = *reinterpret_cast<const float4*>(&(buf)[(r0) + 4][lane * 4]); \
    P##5 = *reinterpret_cast<const float4*>(&(buf)[(r0) + 5][lane * 4]); \
    P##6 = *reinterpret_cast<const float4*>(&(buf)[(r0) + 6][lane * 4]); \
    P##7 = *reinterpret_cast<const float4*>(&(buf)[(r0) + 7][lane * 4]);
#define ST8(P)                                                           \
    row_step(P##0); row_step(P##1); row_step(P##2); row_step(P##3);      \
    row_step(P##4); row_step(P##5); row_step(P##6); row_step(P##7);

        float4 A0, A1, A2, A3, A4, A5, A6, A7;
        float4 B0, B1, B2, B3, B4, B5, B6, B7;

        // chunk 0 (rows 0..15; peel row-0 init)
        {
            const float(*buf)[WW] = sbuf[0];
            RD8(A, buf, 0); RD8(B, buf, 8);
            v0 = A0.x; v1 = A0.y; v2 = A0.z; v3 = A0.w;
            row_step(A1); row_step(A2); row_step(A3);
            row_step(A4); row_step(A5); row_step(A6); row_step(A7);
            ST8(B);
        }
        // chunks 1..15
        for (int k = 1; k < NCH; ++k) {
            __syncthreads();                   // Bk
            const float(*buf)[WW] = sbuf[k & 1];
            RD8(A, buf, 0); RD8(B, buf, 8);
            ST8(A);
            ST8(B);
        }
#undef RD8
#undef ST8
        if (lane == 63) out[blockIdx.x] = v3;
    } else {
        // ---------------- prep waves (wid 0,1,2,4,5,6) ----------------
        // coop chunk-0 split: wid0:2-4 wid1:5-7 wid2:8-10 wid4:11-12 wid5:13-14 wid6:15
        if (wid == 0) { float4 C[3]; load_rows<3>(gp,  2, C); prep_store<3>(C, &sbuf[0][ 2][0], lane); }
        else if (wid == 1) { float4 C[3]; load_rows<3>(gp,  5, C); prep_store<3>(C, &sbuf[0][ 5][0], lane); }
        else if (wid == 2) { float4 C[3]; load_rows<3>(gp,  8, C); prep_store<3>(C, &sbuf[0][ 8][0], lane); }
        else if (wid == 4) { float4 C[2]; load_rows<2>(gp, 11, C); prep_store<2>(C, &sbuf[0][11][0], lane); }
        else if (wid == 5) { float4 C[2]; load_rows<2>(gp, 13, C); prep_store<2>(C, &sbuf[0][13][0], lane); }
        else               { float4 C[1]; load_rows<1>(gp, 15, C); prep_store<1>(C, &sbuf[0][15][0], lane); }

        // steady rows: wid0:0-2 wid1:3-5 wid2:6-8 wid4:9-11 wid5:12-13 wid6:14-15
        if (wid == 0)      prep_run<3>(gp,  0, &sbuf[0][ 0][0], &sbuf[1][ 0][0], lane);
        else if (wid == 1) prep_run<3>(gp,  3, &sbuf[0][ 3][0], &sbuf[1][ 3][0], lane);
        else if (wid == 2) prep_run<3>(gp,  6, &sbuf[0][ 6][0], &sbuf[1][ 6][0], lane);
        else if (wid == 4) prep_run<3>(gp,  9, &sbuf[0][ 9][0], &sbuf[1][ 9][0], lane);
        else if (wid == 5) prep_run<2>(gp, 12, &sbuf[0][12][0], &sbuf[1][12][0], lane);
        else               prep_run<2>(gp, 14, &sbuf[0][14][0], &sbuf[1][14][0], lane);
    }
}

extern "C" void kernel_launch(void* const* d_in, const int* in_sizes, int n_in,
                              void* d_out, int out_size, void* d_ws, size_t ws_size,
                              hipStream_t stream) {
    const float* img = (const float*)d_in[0];
    float* out = (float*)d_out;
    dp_kernel<<<out_size, 448, 0, stream>>>(img, out);
}